// Round 1
// 287.368 us; speedup vs baseline: 1.1619x; 1.1619x over previous
//
#include <hip/hip_runtime.h>
#include <hip/hip_bf16.h>

// B=4, T=2048, EMB=1024, H=16, hd=64. Externals fp32, internals bf16.
// Path A (ws>=40MB): convert_w, convert_x, gemm_lds QKV, attn, gemm_lds out.
//   ws: Wt 8MB | Qb 16MB (Q then attn-out, bijective aliasing) | xb16 16MB.
//   d_out 32MB: K bf16 16MB + Vt bf16 16MB until attn done; out-proj overwrites.
// attn R11: causal-paired blocks (qtA=15-bx heavy + qtB=bx light share staged
// K/V tiles; uniform 17 tile-iters/block, 512 blocks = 2/CU, no tail) +
// T14 async staging (issue next tile's global loads under compute).
#define TT   2048
#define NB   4
#define EMB_ 1024
#define NH   16
#define HD   64

typedef __bf16 bf16x8 __attribute__((ext_vector_type(8)));
typedef float  f32x4  __attribute__((ext_vector_type(4)));
typedef short  short4v __attribute__((ext_vector_type(4)));

__device__ inline short f2bf(float f) {
  unsigned u = __builtin_bit_cast(unsigned, f);
  u += 0x7fffu + ((u >> 16) & 1u);
  return (short)(u >> 16);
}

// pack two fp32 -> two bf16 (RNE) in one dword: low short = a, high short = b
__device__ __forceinline__ unsigned pk2bf(float a, float b) {
  unsigned ua = __builtin_bit_cast(unsigned, a);
  unsigned ub = __builtin_bit_cast(unsigned, b);
  ua += 0x7fffu + ((ua >> 16) & 1u);
  ub += 0x7fffu + ((ub >> 16) & 1u);
  return __builtin_amdgcn_perm(ub, ua, 0x07060302u);
}

__device__ __forceinline__ void gl_lds16(const short* g, short* l) {
  __builtin_amdgcn_global_load_lds(
      (const __attribute__((address_space(1))) unsigned int*)g,
      (__attribute__((address_space(3))) unsigned int*)l, 16, 0, 0);
}

// ---------------------------------------------------------------------------
// Weight convert+transpose: Wt[z][n][k] = bf16(W_z[k][n]).  grid (32,32,4).
// ---------------------------------------------------------------------------
__global__ void convert_w(const float* __restrict__ Wq, const float* __restrict__ Wk,
                          const float* __restrict__ Wv, const float* __restrict__ Wo,
                          short* __restrict__ Wt) {
  __shared__ short tile[32][33];
  const float* W = (blockIdx.z == 0) ? Wq : (blockIdx.z == 1) ? Wk
                   : (blockIdx.z == 2) ? Wv : Wo;
  short* out = Wt + (size_t)blockIdx.z * EMB_ * EMB_;
  int k0 = blockIdx.x * 32, n0 = blockIdx.y * 32;
  int t = threadIdx.x;
  int r = t >> 3, c4 = (t & 7) * 4;
  f32x4 v = *(const f32x4*)&W[(size_t)(k0 + r) * EMB_ + n0 + c4];
#pragma unroll
  for (int j = 0; j < 4; j++) tile[r][c4 + j] = f2bf(v[j]);
  __syncthreads();
  short4v w;
#pragma unroll
  for (int j = 0; j < 4; j++) w[j] = tile[c4 + j][r];
  *(short4v*)&out[(size_t)(n0 + r) * EMB_ + k0 + c4] = w;
}

// ---------------------------------------------------------------------------
// x fp32 -> bf16, 8 elems/thread. grid 4096 x 256.
// ---------------------------------------------------------------------------
__global__ void convert_x(const float* __restrict__ x, short* __restrict__ xb) {
  size_t i = ((size_t)blockIdx.x * 256 + threadIdx.x) * 8;
  f32x4 a = *(const f32x4*)&x[i];
  f32x4 b = *(const f32x4*)&x[i + 4];
  short t[8];
#pragma unroll
  for (int j = 0; j < 4; j++) { t[j] = f2bf(a[j]); t[4 + j] = f2bf(b[j]); }
  *(bf16x8*)&xb[i] = *(const bf16x8*)t;
}

// ---------------------------------------------------------------------------
// gemm_lds: Out = A(bf16) . Wt_z^T + bias_z.  N=K=1024, M = 128*gridDim.x.
// global_load_lds width-16 staging into unpadded As/Bs[128][64] (m97 pattern).
// z==scale_z -> x0.125 (Q proj); z==vmode_z -> bf16 Vt[b][h][d][t]; o32 -> fp32.
// ---------------------------------------------------------------------------
__global__ __launch_bounds__(256, 4)
void gemm_lds(const short* __restrict__ A, const short* __restrict__ WtBase,
              const float* __restrict__ b0, const float* __restrict__ b1,
              const float* __restrict__ b2,
              void* O0, void* O1, void* O2, int vmode_z, int o32, int scale_z) {
  __shared__ __align__(16) short As[128 * 64];
  __shared__ __align__(16) short Bs[128 * 64];
  const int tid = threadIdx.x;
  const int z = blockIdx.z;
  const short* W    = WtBase + (size_t)z * EMB_ * EMB_;
  const float* bias = (z == 0) ? b0 : (z == 1) ? b1 : b2;
  void* Out         = (z == 0) ? O0 : (z == 1) ? O1 : O2;
  const bool vmode = (z == vmode_z);
  const float osc = (z == scale_z) ? 0.125f : 1.0f;

  const int m0 = blockIdx.x * 128;
  const int n0 = blockIdx.y * 128;
  const int wave = tid >> 6, lane = tid & 63;
  const int wm = (wave >> 1) * 64, wn = (wave & 1) * 64;
  const int lg = lane >> 4, lc = lane & 15;
  const int srow = lane >> 3, scol = (lane & 7) * 8;

  f32x4 acc[4][4];
#pragma unroll
  for (int i = 0; i < 4; i++)
#pragma unroll
    for (int j = 0; j < 4; j++) acc[i][j] = (f32x4)0.0f;

  for (int kk = 0; kk < EMB_; kk += 64) {
    __syncthreads();
#pragma unroll
    for (int j = 0; j < 4; j++) {
      int rbase = wave * 32 + j * 8;
      gl_lds16(&A[(size_t)(m0 + rbase + srow) * EMB_ + kk + scol], &As[rbase * 64]);
      gl_lds16(&W[(size_t)(n0 + rbase + srow) * EMB_ + kk + scol], &Bs[rbase * 64]);
    }
    __syncthreads();
#pragma unroll
    for (int ks = 0; ks < 2; ks++) {
      bf16x8 af[4], bfr[4];
#pragma unroll
      for (int mi = 0; mi < 4; mi++)
        af[mi] = *(const bf16x8*)&As[(wm + mi * 16 + lc) * 64 + ks * 32 + lg * 8];
#pragma unroll
      for (int ni = 0; ni < 4; ni++)
        bfr[ni] = *(const bf16x8*)&Bs[(wn + ni * 16 + lc) * 64 + ks * 32 + lg * 8];
#pragma unroll
      for (int mi = 0; mi < 4; mi++)
#pragma unroll
        for (int ni = 0; ni < 4; ni++)
          acc[mi][ni] = __builtin_amdgcn_mfma_f32_16x16x32_bf16(af[mi], bfr[ni], acc[mi][ni], 0, 0, 0);
    }
  }

#pragma unroll
  for (int ni = 0; ni < 4; ni++) {
    int col = n0 + wn + ni * 16 + lc;
    float bv = bias[col];
#pragma unroll
    for (int mi = 0; mi < 4; mi++) {
#pragma unroll
      for (int r = 0; r < 4; r++) {
        int row = m0 + wm + mi * 16 + lg * 4 + r;
        float v = (acc[mi][ni][r] + bv) * osc;
        if (vmode) {
          int b = row >> 11, t = row & (TT - 1);
          int h = col >> 6, d = col & (HD - 1);
          ((short*)Out)[((size_t)((b * NH + h) * HD + d)) * TT + t] = f2bf(v);
        } else if (o32) {
          ((float*)Out)[(size_t)row * EMB_ + col] = v;
        } else {
          ((short*)Out)[(size_t)row * EMB_ + col] = f2bf(v);
        }
      }
    }
  }
}

// ---------------------------------------------------------------------------
// gemm_bt: fallback (fp32 or bf16 A via VGPR staging, padded LDS).
// ---------------------------------------------------------------------------
__global__ __launch_bounds__(256, 4)
void gemm_bt(const void* __restrict__ A, int a32,
             const short* __restrict__ WtBase,
             const float* __restrict__ b0, const float* __restrict__ b1,
             const float* __restrict__ b2,
             void* O0, void* O1, void* O2, int vmode_z, int o32, int scale_z) {
  __shared__ __align__(16) short As[128 * 72];
  __shared__ __align__(16) short Bs[128 * 72];
  const int tid = threadIdx.x;
  const int z = blockIdx.z;
  const short* W    = WtBase + (size_t)z * EMB_ * EMB_;
  const float* bias = (z == 0) ? b0 : (z == 1) ? b1 : b2;
  void* Out         = (z == 0) ? O0 : (z == 1) ? O1 : O2;
  const bool vmode = (z == vmode_z);
  const float osc = (z == scale_z) ? 0.125f : 1.0f;

  const int m0 = blockIdx.x * 128;
  const int n0 = blockIdx.y * 128;
  const int wave = tid >> 6, lane = tid & 63;
  const int wm = (wave >> 1) * 64, wn = (wave & 1) * 64;
  const int lg = lane >> 4, lc = lane & 15;

  f32x4 acc[4][4];
#pragma unroll
  for (int i = 0; i < 4; i++)
#pragma unroll
    for (int j = 0; j < 4; j++) acc[i][j] = (f32x4)0.0f;

  for (int kk = 0; kk < EMB_; kk += 64) {
    __syncthreads();
#pragma unroll
    for (int i = 0; i < 4; i++) {
      int s = i * 256 + tid;
      int row = s >> 3, c = s & 7;
      size_t base = (size_t)(m0 + row) * EMB_ + kk + c * 8;
      bf16x8 av;
      if (a32) {
        const float* Af = (const float*)A + base;
        f32x4 u0 = *(const f32x4*)Af;
        f32x4 u1 = *(const f32x4*)(Af + 4);
        short tmp[8];
#pragma unroll
        for (int j = 0; j < 4; j++) { tmp[j] = f2bf(u0[j]); tmp[4 + j] = f2bf(u1[j]); }
        av = *(const bf16x8*)tmp;
      } else {
        av = *(const bf16x8*)((const short*)A + base);
      }
      *(bf16x8*)&As[row * 72 + c * 8] = av;
    }
#pragma unroll
    for (int i = 0; i < 4; i++) {
      int s = i * 256 + tid;
      int row = s >> 3, c = s & 7;
      *(bf16x8*)&Bs[row * 72 + c * 8] =
          *(const bf16x8*)&W[(size_t)(n0 + row) * EMB_ + kk + c * 8];
    }
    __syncthreads();
#pragma unroll
    for (int ks = 0; ks < 2; ks++) {
      bf16x8 af[4], bfr[4];
#pragma unroll
      for (int mi = 0; mi < 4; mi++)
        af[mi] = *(const bf16x8*)&As[(wm + mi * 16 + lc) * 72 + ks * 32 + lg * 8];
#pragma unroll
      for (int ni = 0; ni < 4; ni++)
        bfr[ni] = *(const bf16x8*)&Bs[(wn + ni * 16 + lc) * 72 + ks * 32 + lg * 8];
#pragma unroll
      for (int mi = 0; mi < 4; mi++)
#pragma unroll
        for (int ni = 0; ni < 4; ni++)
          acc[mi][ni] = __builtin_amdgcn_mfma_f32_16x16x32_bf16(af[mi], bfr[ni], acc[mi][ni], 0, 0, 0);
    }
  }

#pragma unroll
  for (int ni = 0; ni < 4; ni++) {
    int col = n0 + wn + ni * 16 + lc;
    float bv = bias[col];
#pragma unroll
    for (int mi = 0; mi < 4; mi++) {
#pragma unroll
      for (int r = 0; r < 4; r++) {
        int row = m0 + wm + mi * 16 + lg * 4 + r;
        float v = (acc[mi][ni][r] + bv) * osc;
        if (vmode) {
          int b = row >> 11, t = row & (TT - 1);
          int h = col >> 6, d = col & (HD - 1);
          ((short*)Out)[((size_t)((b * NH + h) * HD + d)) * TT + t] = f2bf(v);
        } else if (o32) {
          ((float*)Out)[(size_t)row * EMB_ + col] = v;
        } else {
          ((short*)Out)[(size_t)row * EMB_ + col] = f2bf(v);
        }
      }
    }
  }
}

// ---------------------------------------------------------------------------
// Flash attention, causal, fixed-max softmax (M=6). Q pre-scaled by 1/8.
// R11: causal-paired blocks. grid (8, B*H). Block bx handles q-tiles
//   qtA = 15-bx (heavy) and qtB = bx (light); qtB's key range is a prefix of
//   qtA's, so one staged K/V tile feeds both -> uniform 17 tile-iters/block,
//   512 blocks = 2 blocks/CU resident, zero tail.
// T14: next tile's K/V global loads issued into regs right after the LDS
//   write of the current tile; HBM latency hides under MFMA+softmax.
// S^T formulation: s4[ni] = mfma(kf, qf) -> lane holds S^T[key][q=lc];
//   per-lane scalar lsum; P packed via v_perm into ds_write_b64.
// O aliases Q (read once at start, written at end, bijective).
// ---------------------------------------------------------------------------
__global__ __launch_bounds__(256, 2)
void attn_fwd(const short* Q, const short* K, const short* Vt, short* O) {
  __shared__ __align__(16) short Ks[128 * 72];   // [key-in-tile][d]
  __shared__ __align__(16) short Vs[64 * 136];   // [d][key-in-tile]
  __shared__ __align__(16) short Ps[4][16 * 72]; // per-wave P: [q][key-chunk]
  const int tid = threadIdx.x;
  const int bh = blockIdx.y;
  const int b = bh >> 4, h = bh & (NH - 1);
  const int qtA = 15 - (int)blockIdx.x;          // heavy tile
  const int qtB = (int)blockIdx.x;               // light tile (qtB < qtA)
  const int wave = tid >> 6, lane = tid & 63;
  const int lg = lane >> 4, lc = lane & 15;

  // Q fragments for both tiles: [tile][rb][ks]
  bf16x8 qf[2][2][2];
#pragma unroll
  for (int pt = 0; pt < 2; pt++) {
    const int qt = pt ? qtB : qtA;
#pragma unroll
    for (int rb = 0; rb < 2; rb++) {
      const int qrow = b * TT + qt * 128 + rb * 64 + wave * 16 + lc;
      qf[pt][rb][0] = *(const bf16x8*)&Q[(size_t)qrow * EMB_ + h * HD + lg * 8];
      qf[pt][rb][1] = *(const bf16x8*)&Q[(size_t)qrow * EMB_ + h * HD + 32 + lg * 8];
    }
  }

  f32x4 o[2][2][4];
#pragma unroll
  for (int pt = 0; pt < 2; pt++)
#pragma unroll
    for (int rb = 0; rb < 2; rb++)
#pragma unroll
      for (int ni = 0; ni < 4; ni++) o[pt][rb][ni] = (f32x4)0.0f;
  float lsum[2][2] = {{0.f, 0.f}, {0.f, 0.f}};

  // T14 staging registers (K and V tile halves, 16B per load, 8 loads/thread)
  bf16x8 kreg[4], vreg[4];

  auto issue_loads = [&](int ktt) {
    const int kb = ktt * 128;
#pragma unroll
    for (int i = 0; i < 4; i++) {
      int s = i * 256 + tid;
      kreg[i] = *(const bf16x8*)&K[(size_t)(b * TT + kb + (s >> 3)) * EMB_ + h * HD + (s & 7) * 8];
      vreg[i] = *(const bf16x8*)&Vt[(size_t)(bh * HD + (s >> 4)) * TT + kb + (s & 15) * 8];
    }
  };
  auto write_lds = [&]() {
#pragma unroll
    for (int i = 0; i < 4; i++) {
      int s = i * 256 + tid;
      *(bf16x8*)&Ks[(s >> 3) * 72 + (s & 7) * 8] = kreg[i];
      *(bf16x8*)&Vs[(s >> 4) * 136 + (s & 15) * 8] = vreg[i];
    }
  };

  auto compute_tile = [&](int qt, bf16x8 (&qft)[2][2], f32x4 (&ot)[2][4],
                          float (&ls)[2], int ktt) {
    const int q0 = qt * 128;
#pragma unroll
    for (int chunk = 0; chunk < 2; chunk++) {
      const int cg = 2 * ktt + chunk;              // global 64-key chunk index
#pragma unroll
      for (int rb = 0; rb < 2; rb++) {
        const int qbase = q0 + rb * 64 + wave * 16; // first q-row of this rb
        if (cg * 64 > qbase + 15) continue;         // fully masked (uniform)
        const bool diag = (cg == 2 * qt + rb);
        const int qg = qbase + lc;                  // this lane's q row

        // S^T = K Q^T for this 64-key chunk (swapped operands)
        f32x4 s4[4];
#pragma unroll
        for (int ni = 0; ni < 4; ni++) s4[ni] = (f32x4)0.0f;
#pragma unroll
        for (int ks = 0; ks < 2; ks++) {
          bf16x8 kf[4];
#pragma unroll
          for (int ni = 0; ni < 4; ni++)
            kf[ni] = *(const bf16x8*)&Ks[(chunk * 64 + ni * 16 + lc) * 72 + ks * 32 + lg * 8];
#pragma unroll
          for (int ni = 0; ni < 4; ni++)
            s4[ni] = __builtin_amdgcn_mfma_f32_16x16x32_bf16(kf[ni], qft[rb][ks], s4[ni], 0, 0, 0);
        }

        // p = exp(s - 6); per-lane scalar lsum; pack 4 consecutive keys -> b64
#pragma unroll
        for (int ni = 0; ni < 4; ni++) {
          float p[4];
#pragma unroll
          for (int r = 0; r < 4; r++) {
            float v = s4[ni][r];
            if (diag) {
              int keyg = cg * 64 + ni * 16 + lg * 4 + r;
              if (keyg > qg) v = -1e30f;
            }
            p[r] = __expf(v - 6.0f);
            ls[rb] += p[r];
          }
          uint2 dd;
          dd.x = pk2bf(p[0], p[1]);
          dd.y = pk2bf(p[2], p[3]);
          *(uint2*)&Ps[wave][lc * 72 + ni * 16 + lg * 4] = dd;
        }
        // in-wave LDS write->read ordered by lgkmcnt; Ps is per-wave

#pragma unroll
        for (int ks2 = 0; ks2 < 2; ks2++) {
          bf16x8 pa = *(const bf16x8*)&Ps[wave][lc * 72 + ks2 * 32 + lg * 8];
          bf16x8 vf[4];
#pragma unroll
          for (int ni = 0; ni < 4; ni++)
            vf[ni] = *(const bf16x8*)&Vs[(ni * 16 + lc) * 136 + chunk * 64 + ks2 * 32 + lg * 8];
#pragma unroll
          for (int ni = 0; ni < 4; ni++)
            ot[rb][ni] = __builtin_amdgcn_mfma_f32_16x16x32_bf16(pa, vf[ni], ot[rb][ni], 0, 0, 0);
        }
      }
    }
  };

  const int ntiles = qtA + 1;                     // 128-key tiles (heavy tile)

  issue_loads(0);
  for (int ktt = 0; ktt < ntiles; ktt++) {
    __syncthreads();
    write_lds();
    if (ktt + 1 < ntiles) issue_loads(ktt + 1);   // T14: hide under compute
    __syncthreads();

    compute_tile(qtA, qf[0], o[0], lsum[0], ktt);
    if (ktt <= qtB)
      compute_tile(qtB, qf[1], o[1], lsum[1], ktt);
  }

  // reduce lsum (held per-lane for q=lc) and redistribute to q=lg*4+r lanes
#pragma unroll
  for (int pt = 0; pt < 2; pt++) {
    const int qt = pt ? qtB : qtA;
    const int q0 = qt * 128;
    float linv[2][4];
#pragma unroll
    for (int rb = 0; rb < 2; rb++) {
      float red = lsum[pt][rb];
      red += __shfl_xor(red, 16, 64);
      red += __shfl_xor(red, 32, 64);
#pragma unroll
      for (int r = 0; r < 4; r++)
        linv[rb][r] = 1.0f / __shfl(red, lg * 4 + r, 64);
    }
#pragma unroll
    for (int rb = 0; rb < 2; rb++) {
#pragma unroll
      for (int ni = 0; ni < 4; ni++) {
#pragma unroll
        for (int r = 0; r < 4; r++) {
          int token = b * TT + q0 + rb * 64 + wave * 16 + lg * 4 + r;
          int col = h * HD + ni * 16 + lc;
          O[(size_t)token * EMB_ + col] = f2bf(o[pt][rb][ni][r] * linv[rb][r]);
        }
      }
    }
  }
}

// ---------------------------------------------------------------------------
extern "C" void kernel_launch(void* const* d_in, const int* in_sizes, int n_in,
                              void* d_out, int out_size, void* d_ws, size_t ws_size,
                              hipStream_t stream) {
  const float* x  = (const float*)d_in[0];
  const float* Wq = (const float*)d_in[1];
  const float* bq = (const float*)d_in[2];
  const float* Wk = (const float*)d_in[3];
  const float* bk = (const float*)d_in[4];
  const float* Wv = (const float*)d_in[5];
  const float* bv = (const float*)d_in[6];
  const float* Wo = (const float*)d_in[7];
  const float* bo = (const float*)d_in[8];

  short* Wt = (short*)d_ws;                        // 8MB bf16 transposed weights
  short* Qb = Wt + (size_t)4 * EMB_ * EMB_;        // 16MB: Q / attn-out

  convert_w<<<dim3(32, 32, 4), 256, 0, stream>>>(Wq, Wk, Wv, Wo, Wt);

  if (ws_size >= (size_t)40 * 1024 * 1024) {
    short* xb16 = Qb + (size_t)NB * TT * EMB_;     // 16MB bf16 x
    short* Kb   = (short*)d_out;                   // 16MB bf16 K
    short* Vtb  = Kb + (size_t)NB * TT * EMB_;     // 16MB bf16 Vt
    convert_x<<<dim3(4096), 256, 0, stream>>>(x, xb16);
    gemm_lds<<<dim3(64, 8, 3), 256, 0, stream>>>(
        xb16, Wt, bq, bk, bv, Qb, Kb, Vtb, /*vmode_z=*/2, /*o32=*/0, /*scale_z=*/0);
    attn_fwd<<<dim3(8, 64), 256, 0, stream>>>(Qb, Kb, Vtb, Qb);
    gemm_lds<<<dim3(64, 8, 1), 256, 0, stream>>>(
        Qb, Wt + (size_t)3 * EMB_ * EMB_, bo, bo, bo,
        d_out, d_out, d_out, /*vmode_z=*/-1, /*o32=*/1, /*scale_z=*/-1);
  } else if (ws_size >= (size_t)24 * 1024 * 1024) {
    short* Kb  = (short*)d_out;
    short* Vtb = Kb + (size_t)NB * TT * EMB_;
    gemm_bt<<<dim3(64, 8, 3), 256, 0, stream>>>(
        x, 1, Wt, bq, bk, bv, Qb, Kb, Vtb, 2, 0, 0);
    attn_fwd<<<dim3(8, 64), 256, 0, stream>>>(Qb, Kb, Vtb, Qb);
    gemm_bt<<<dim3(64, 8, 1), 256, 0, stream>>>(
        Qb, 0, Wt + (size_t)3 * EMB_ * EMB_, bo, bo, bo,
        d_out, d_out, d_out, -1, 1, -1);
  } else {
    for (int b = 0; b < NB; b++) {
      const float* xb = x + (size_t)b * TT * EMB_;
      float* outb = (float*)d_out + (size_t)b * TT * EMB_;
      short* Kb  = (short*)outb;
      short* Vtb = Kb + (size_t)TT * EMB_;
      gemm_bt<<<dim3(16, 8, 3), 256, 0, stream>>>(
          xb, 1, Wt, bq, bk, bv, Qb, Kb, Vtb, 2, 0, 0);
      attn_fwd<<<dim3(8, 16), 256, 0, stream>>>(Qb, Kb, Vtb, Qb);
      gemm_bt<<<dim3(16, 8, 1), 256, 0, stream>>>(
          Qb, 0, Wt + (size_t)3 * EMB_ * EMB_, bo, bo, bo,
          outb, outb, outb, -1, 1, -1);
    }
  }
}